// Round 4
// baseline (81.593 us; speedup 1.0000x reference)
//
#include <hip/hip_runtime.h>

// Elementwise fuzzify: y[r, i] = clip(diag[r] * aug_r(x[i]) + b[r], 0, 1).
// R4: one-output-row-per-block layout. Previous kernel interleaved 9 write
// streams 32 MB apart per wave (same channel/bank mapping at any pow2
// interleave -> poor DRAM locality). Now each block writes one contiguous
// 32 KB span of one row (nt stores); x re-read per row via CACHED loads
// (33.5 MB fits the 256 MB LLC -> ~no extra HBM fetch). Row index is
// block-uniform -> 1 aug per thread instead of 9.

typedef float f32x4 __attribute__((ext_vector_type(4)));

constexpr int ITERS = 8;                    // float4s per thread
constexpr int CHUNK_F4 = 256 * ITERS;       // 2048 float4s = 32 KB per block

__global__ __launch_bounds__(256) void fuzzify_kernel(
    const float* __restrict__ x,
    const float* __restrict__ p_td_c,
    const float* __restrict__ p_td_s,
    const float* __restrict__ p_dl_s,
    const float* __restrict__ p_dl_cw,
    const float* __restrict__ p_dl_sw,
    const float* __restrict__ p_dl_ssw,
    float* __restrict__ out, int n, int chunks_per_row)
{
    const float ms = 0.01f;
    const float td_c = p_td_c[0];
    const float td_s = fabsf(p_td_s[0] - ms) + ms;
    const float dl_s = fabsf(p_dl_s[0] - ms) + ms;

    const float slope_width = 1.0f / dl_s;
    const float cw  = fabsf(p_dl_cw[0]);
    const float sw  = fabsf(p_dl_sw[0]);
    const float ssw = fabsf(p_dl_ssw[0]);
    const float c_half  = 0.5f * cw;
    const float s_half  = 0.5f * sw;
    const float ss_half = 0.5f * ssw;

    const float d1 = dl_s * s_half + 1.0f;
    const float c1 = c_half + slope_width + s_half;
    const float d2 = dl_s * ss_half + 1.0f;
    const float c2 = c_half + 2.0f * slope_width + sw + ss_half;
    const float c3 = c_half + sw + 3.0f * slope_width + ssw;
    const float d3 = -dl_s * c3 + 1.0f;
    const float a  = td_c * td_s;

    // Row 2's aug = -x folded into slope: dl_s * (-x) == (-dl_s) * x.
    const float slope[9] = { -td_s, td_s, -dl_s, -dl_s, -dl_s, -dl_s, -dl_s, -dl_s, dl_s };
    const float bias[9]  = { 1.0f + a, -a, d3, d2, d1, dl_s * c_half + 1.0f, d1, d2, d3 };
    const float offs[9]  = { 0.0f, 0.0f, 0.0f, c2, c1, 0.0f, -c1, -c2, 0.0f };

    const int bid   = blockIdx.x;
    const int r     = bid / chunks_per_row;       // block-uniform row 0..8
    const int chunk = bid - r * chunks_per_row;

    const float s  = slope[r];
    const float b  = bias[r];
    const float of = offs[r];
    const bool  is_abs = (r >= 3) && (r <= 7);

    const f32x4* __restrict__ x4 = (const f32x4*)x;
    float* __restrict__ orow = out + (size_t)r * (size_t)n;

    const int base4 = chunk * CHUNK_F4 + threadIdx.x;

    #pragma unroll
    for (int k = 0; k < ITERS; ++k) {
        const int i4 = base4 + k * 256;
        f32x4 v = x4[i4];                 // cached load: LLC-hit for 8/9 rows
        f32x4 o;
        #pragma unroll
        for (int j = 0; j < 4; ++j) {
            float xx = v[j];
            float t = is_abs ? fabsf(xx + of) : xx;
            float y = fmaf(s, t, b);
            o[j] = fminf(fmaxf(y, 0.0f), 1.0f);   // v_med3_f32
        }
        __builtin_nontemporal_store(o, (f32x4*)(orow + ((size_t)i4 << 2)));
    }
}

extern "C" void kernel_launch(void* const* d_in, const int* in_sizes, int n_in,
                              void* d_out, int out_size, void* d_ws, size_t ws_size,
                              hipStream_t stream) {
    const float* x        = (const float*)d_in[0];
    const float* p_td_c   = (const float*)d_in[1];
    const float* p_td_s   = (const float*)d_in[2];
    const float* p_dl_s   = (const float*)d_in[3];
    const float* p_dl_cw  = (const float*)d_in[4];
    const float* p_dl_sw  = (const float*)d_in[5];
    const float* p_dl_ssw = (const float*)d_in[6];
    float* out = (float*)d_out;

    const int n = in_sizes[0];                    // 2^23
    const int n4 = n >> 2;
    const int chunks_per_row = n4 / CHUNK_F4;     // 1024
    const int grid = 9 * chunks_per_row;          // 9216 blocks

    fuzzify_kernel<<<grid, 256, 0, stream>>>(
        x, p_td_c, p_td_s, p_dl_s, p_dl_cw, p_dl_sw, p_dl_ssw, out, n, chunks_per_row);
}

// Round 5
// 66.548 us; speedup vs baseline: 1.2261x; 1.2261x over previous
//
#include <hip/hip_runtime.h>

// Elementwise fuzzify: y[r, i] = clip(diag[r] * aug_r(x[i]) + b[r], 0, 1).
// R5: read-once + long per-wave write runs. R3 (9x1KB interleaved runs/wave,
// minimal traffic) = 4.54 TB/s; R4 (8KB contiguous runs, but 9x re-read of x
// missed LLC) = ~6+ TB/s effective on 2x traffic. Combine: each wave loads
// its 8KB of x once (8 independent nt loads -> MLP), then writes 9 streams
// as contiguous 8KB runs each, stores grouped per stream.

typedef float f32x4 __attribute__((ext_vector_type(4)));

constexpr int ITERS = 8;                    // float4s per thread
constexpr int CHUNK_F4 = 256 * ITERS;       // 2048 float4s = 32 KB per block

__global__ __launch_bounds__(256) void fuzzify_kernel(
    const float* __restrict__ x,
    const float* __restrict__ p_td_c,
    const float* __restrict__ p_td_s,
    const float* __restrict__ p_dl_s,
    const float* __restrict__ p_dl_cw,
    const float* __restrict__ p_dl_sw,
    const float* __restrict__ p_dl_ssw,
    float* __restrict__ out, int n)
{
    const float ms = 0.01f;
    const float td_c = p_td_c[0];
    const float td_s = fabsf(p_td_s[0] - ms) + ms;
    const float dl_s = fabsf(p_dl_s[0] - ms) + ms;

    const float slope_width = 1.0f / dl_s;
    const float cw  = fabsf(p_dl_cw[0]);
    const float sw  = fabsf(p_dl_sw[0]);
    const float ssw = fabsf(p_dl_ssw[0]);
    const float c_half  = 0.5f * cw;
    const float s_half  = 0.5f * sw;
    const float ss_half = 0.5f * ssw;

    const float d1 = dl_s * s_half + 1.0f;
    const float c1 = c_half + slope_width + s_half;
    const float d2 = dl_s * ss_half + 1.0f;
    const float c2 = c_half + 2.0f * slope_width + sw + ss_half;
    const float c3 = c_half + sw + 3.0f * slope_width + ssw;
    const float d3 = -dl_s * c3 + 1.0f;
    const float a  = td_c * td_s;

    // Row 2's aug = -x folded into slope: dl_s * (-x) == (-dl_s) * x.
    const float slope[9] = { -td_s, td_s, -dl_s, -dl_s, -dl_s, -dl_s, -dl_s, -dl_s, dl_s };
    const float bias[9]  = { 1.0f + a, -a, d3, d2, d1, dl_s * c_half + 1.0f, d1, d2, d3 };
    const float offs[9]  = { 0.0f, 0.0f, 0.0f, c2, c1, 0.0f, -c1, -c2, 0.0f };

    const int lane = threadIdx.x & 63;
    const int wav  = threadIdx.x >> 6;
    // wave w owns a contiguous 8KB span: float4 indices [blk*2048 + w*512, +512)
    const int i0 = blockIdx.x * CHUNK_F4 + wav * (64 * ITERS) + lane;

    const f32x4* __restrict__ x4 = (const f32x4*)x;

    // Load this thread's 8 float4s up front (independent -> 8 in flight).
    f32x4 xv[ITERS];
    #pragma unroll
    for (int k = 0; k < ITERS; ++k)
        xv[k] = __builtin_nontemporal_load(&x4[i0 + k * 64]);

    // For each output row: compute + store 8 consecutive 1KB wave-runs
    // back-to-back (8KB contiguous per wave per stream).
    #pragma unroll
    for (int r = 0; r < 9; ++r) {
        const float s  = slope[r];
        const float b  = bias[r];
        const float of = offs[r];
        const bool  is_abs = (r >= 3) && (r <= 7);
        float* __restrict__ orow = out + (size_t)r * (size_t)n;

        #pragma unroll
        for (int k = 0; k < ITERS; ++k) {
            f32x4 v = xv[k];
            f32x4 o;
            #pragma unroll
            for (int j = 0; j < 4; ++j) {
                float t = is_abs ? fabsf(v[j] + of) : v[j];
                float y = fmaf(s, t, b);
                o[j] = fminf(fmaxf(y, 0.0f), 1.0f);   // v_med3_f32
            }
            __builtin_nontemporal_store(o,
                (f32x4*)(orow + ((size_t)(i0 + k * 64) << 2)));
        }
    }
}

extern "C" void kernel_launch(void* const* d_in, const int* in_sizes, int n_in,
                              void* d_out, int out_size, void* d_ws, size_t ws_size,
                              hipStream_t stream) {
    const float* x        = (const float*)d_in[0];
    const float* p_td_c   = (const float*)d_in[1];
    const float* p_td_s   = (const float*)d_in[2];
    const float* p_dl_s   = (const float*)d_in[3];
    const float* p_dl_cw  = (const float*)d_in[4];
    const float* p_dl_sw  = (const float*)d_in[5];
    const float* p_dl_ssw = (const float*)d_in[6];
    float* out = (float*)d_out;

    const int n = in_sizes[0];                 // 2^23
    const int n4 = n >> 2;                     // 2^21 float4s
    const int grid = n4 / CHUNK_F4;            // 1024 blocks (exact)

    fuzzify_kernel<<<grid, 256, 0, stream>>>(
        x, p_td_c, p_td_s, p_dl_s, p_dl_cw, p_dl_sw, p_dl_ssw, out, n);
}

// Round 6
// 63.027 us; speedup vs baseline: 1.2946x; 1.0559x over previous
//
#include <hip/hip_runtime.h>

// Elementwise fuzzify: y[r, i] = clip(diag[r] * aug_r(x[i]) + b[r], 0, 1).
// R6: run-length ladder continues. R3 1KB runs=4.54 TB/s, R5 8KB runs=5.05,
// pure contiguous (fill) ~6.9. Double per-wave per-stream run to 16 KB:
// ITERS=16, each wave owns 16KB per row, stores grouped per row back-to-back.
// Traffic stays minimal: x read once (nt), 302 MB written once (nt).

typedef float f32x4 __attribute__((ext_vector_type(4)));

constexpr int ITERS = 16;                   // float4s per thread
constexpr int CHUNK_F4 = 256 * ITERS;       // 4096 float4s = 64 KB per block

__global__ __launch_bounds__(256) void fuzzify_kernel(
    const float* __restrict__ x,
    const float* __restrict__ p_td_c,
    const float* __restrict__ p_td_s,
    const float* __restrict__ p_dl_s,
    const float* __restrict__ p_dl_cw,
    const float* __restrict__ p_dl_sw,
    const float* __restrict__ p_dl_ssw,
    float* __restrict__ out, int n)
{
    const float ms = 0.01f;
    const float td_c = p_td_c[0];
    const float td_s = fabsf(p_td_s[0] - ms) + ms;
    const float dl_s = fabsf(p_dl_s[0] - ms) + ms;

    const float slope_width = 1.0f / dl_s;
    const float cw  = fabsf(p_dl_cw[0]);
    const float sw  = fabsf(p_dl_sw[0]);
    const float ssw = fabsf(p_dl_ssw[0]);
    const float c_half  = 0.5f * cw;
    const float s_half  = 0.5f * sw;
    const float ss_half = 0.5f * ssw;

    const float d1 = dl_s * s_half + 1.0f;
    const float c1 = c_half + slope_width + s_half;
    const float d2 = dl_s * ss_half + 1.0f;
    const float c2 = c_half + 2.0f * slope_width + sw + ss_half;
    const float c3 = c_half + sw + 3.0f * slope_width + ssw;
    const float d3 = -dl_s * c3 + 1.0f;
    const float a  = td_c * td_s;

    // Row 2's aug = -x folded into slope: dl_s * (-x) == (-dl_s) * x.
    const float slope[9] = { -td_s, td_s, -dl_s, -dl_s, -dl_s, -dl_s, -dl_s, -dl_s, dl_s };
    const float bias[9]  = { 1.0f + a, -a, d3, d2, d1, dl_s * c_half + 1.0f, d1, d2, d3 };
    const float offs[9]  = { 0.0f, 0.0f, 0.0f, c2, c1, 0.0f, -c1, -c2, 0.0f };

    const int lane = threadIdx.x & 63;
    const int wav  = threadIdx.x >> 6;
    // wave w owns a contiguous 16KB span: float4 idx [blk*4096 + w*1024, +1024)
    const int i0 = blockIdx.x * CHUNK_F4 + wav * (64 * ITERS) + lane;

    const f32x4* __restrict__ x4 = (const f32x4*)x;

    // Load this thread's 16 float4s up front (independent -> 16 in flight).
    f32x4 xv[ITERS];
    #pragma unroll
    for (int k = 0; k < ITERS; ++k)
        xv[k] = __builtin_nontemporal_load(&x4[i0 + k * 64]);

    // For each output row: 16 consecutive 1KB wave-runs back-to-back
    // (16KB contiguous per wave per stream).
    #pragma unroll
    for (int r = 0; r < 9; ++r) {
        const float s  = slope[r];
        const float b  = bias[r];
        const float of = offs[r];
        const bool  is_abs = (r >= 3) && (r <= 7);
        float* __restrict__ orow = out + (size_t)r * (size_t)n;

        #pragma unroll
        for (int k = 0; k < ITERS; ++k) {
            f32x4 v = xv[k];
            f32x4 o;
            #pragma unroll
            for (int j = 0; j < 4; ++j) {
                float t = is_abs ? fabsf(v[j] + of) : v[j];
                float y = fmaf(s, t, b);
                o[j] = fminf(fmaxf(y, 0.0f), 1.0f);   // v_med3_f32
            }
            __builtin_nontemporal_store(o,
                (f32x4*)(orow + ((size_t)(i0 + k * 64) << 2)));
        }
    }
}

extern "C" void kernel_launch(void* const* d_in, const int* in_sizes, int n_in,
                              void* d_out, int out_size, void* d_ws, size_t ws_size,
                              hipStream_t stream) {
    const float* x        = (const float*)d_in[0];
    const float* p_td_c   = (const float*)d_in[1];
    const float* p_td_s   = (const float*)d_in[2];
    const float* p_dl_s   = (const float*)d_in[3];
    const float* p_dl_cw  = (const float*)d_in[4];
    const float* p_dl_sw  = (const float*)d_in[5];
    const float* p_dl_ssw = (const float*)d_in[6];
    float* out = (float*)d_out;

    const int n = in_sizes[0];                 // 2^23
    const int n4 = n >> 2;                     // 2^21 float4s
    const int grid = n4 / CHUNK_F4;            // 512 blocks (exact)

    fuzzify_kernel<<<grid, 256, 0, stream>>>(
        x, p_td_c, p_td_s, p_dl_s, p_dl_cw, p_dl_sw, p_dl_ssw, out, n);
}

// Round 7
// 58.968 us; speedup vs baseline: 1.3837x; 1.0688x over previous
//
#include <hip/hip_runtime.h>

// Elementwise fuzzify: y[r, i] = clip(diag[r] * aug_r(x[i]) + b[r], 0, 1).
// R7: run-length ladder + row-phase sync. Ladder so far (eff. BW incl. read):
// 1KB runs 4.54 / 8KB 5.05 / 16KB 5.33 TB/s; fill-kernel write rate 6.9.
// This round: ITERS=32 -> 128KB contiguous block run per row, grid=256 =
// exactly 1 block/CU so (a) every CU emits a single row-stream at a time,
// (b) all blocks start synchronized -> whole chip writes the same output row
// concurrently at adjacent addresses (DRAM page coherence per channel).

typedef float f32x4 __attribute__((ext_vector_type(4)));

constexpr int ITERS = 32;                   // float4s per thread (128 VGPRs)
constexpr int CHUNK_F4 = 256 * ITERS;       // 8192 float4s = 128 KB per block

__global__ __launch_bounds__(256, 1) void fuzzify_kernel(
    const float* __restrict__ x,
    const float* __restrict__ p_td_c,
    const float* __restrict__ p_td_s,
    const float* __restrict__ p_dl_s,
    const float* __restrict__ p_dl_cw,
    const float* __restrict__ p_dl_sw,
    const float* __restrict__ p_dl_ssw,
    float* __restrict__ out, int n)
{
    const float ms = 0.01f;
    const float td_c = p_td_c[0];
    const float td_s = fabsf(p_td_s[0] - ms) + ms;
    const float dl_s = fabsf(p_dl_s[0] - ms) + ms;

    const float slope_width = 1.0f / dl_s;
    const float cw  = fabsf(p_dl_cw[0]);
    const float sw  = fabsf(p_dl_sw[0]);
    const float ssw = fabsf(p_dl_ssw[0]);
    const float c_half  = 0.5f * cw;
    const float s_half  = 0.5f * sw;
    const float ss_half = 0.5f * ssw;

    const float d1 = dl_s * s_half + 1.0f;
    const float c1 = c_half + slope_width + s_half;
    const float d2 = dl_s * ss_half + 1.0f;
    const float c2 = c_half + 2.0f * slope_width + sw + ss_half;
    const float c3 = c_half + sw + 3.0f * slope_width + ssw;
    const float d3 = -dl_s * c3 + 1.0f;
    const float a  = td_c * td_s;

    // Row 2's aug = -x folded into slope: dl_s * (-x) == (-dl_s) * x.
    const float slope[9] = { -td_s, td_s, -dl_s, -dl_s, -dl_s, -dl_s, -dl_s, -dl_s, dl_s };
    const float bias[9]  = { 1.0f + a, -a, d3, d2, d1, dl_s * c_half + 1.0f, d1, d2, d3 };
    const float offs[9]  = { 0.0f, 0.0f, 0.0f, c2, c1, 0.0f, -c1, -c2, 0.0f };

    const int lane = threadIdx.x & 63;
    const int wav  = threadIdx.x >> 6;
    // wave w owns a contiguous 32KB span; block covers contiguous 128KB.
    const int i0 = blockIdx.x * CHUNK_F4 + wav * (64 * ITERS) + lane;

    const f32x4* __restrict__ x4 = (const f32x4*)x;

    // Load this thread's 32 float4s up front (independent -> deep MLP).
    f32x4 xv[ITERS];
    #pragma unroll
    for (int k = 0; k < ITERS; ++k)
        xv[k] = __builtin_nontemporal_load(&x4[i0 + k * 64]);

    // For each output row: 32 consecutive 1KB wave-runs back-to-back
    // (32KB contiguous per wave, 128KB per block, per stream).
    #pragma unroll
    for (int r = 0; r < 9; ++r) {
        const float s  = slope[r];
        const float b  = bias[r];
        const float of = offs[r];
        const bool  is_abs = (r >= 3) && (r <= 7);
        float* __restrict__ orow = out + (size_t)r * (size_t)n;

        #pragma unroll
        for (int k = 0; k < ITERS; ++k) {
            f32x4 v = xv[k];
            f32x4 o;
            #pragma unroll
            for (int j = 0; j < 4; ++j) {
                float t = is_abs ? fabsf(v[j] + of) : v[j];
                float y = fmaf(s, t, b);
                o[j] = fminf(fmaxf(y, 0.0f), 1.0f);   // v_med3_f32
            }
            __builtin_nontemporal_store(o,
                (f32x4*)(orow + ((size_t)(i0 + k * 64) << 2)));
        }
    }
}

extern "C" void kernel_launch(void* const* d_in, const int* in_sizes, int n_in,
                              void* d_out, int out_size, void* d_ws, size_t ws_size,
                              hipStream_t stream) {
    const float* x        = (const float*)d_in[0];
    const float* p_td_c   = (const float*)d_in[1];
    const float* p_td_s   = (const float*)d_in[2];
    const float* p_dl_s   = (const float*)d_in[3];
    const float* p_dl_cw  = (const float*)d_in[4];
    const float* p_dl_sw  = (const float*)d_in[5];
    const float* p_dl_ssw = (const float*)d_in[6];
    float* out = (float*)d_out;

    const int n = in_sizes[0];                 // 2^23
    const int n4 = n >> 2;                     // 2^21 float4s
    const int grid = n4 / CHUNK_F4;            // 256 blocks (exact) = 1/CU

    fuzzify_kernel<<<grid, 256, 0, stream>>>(
        x, p_td_c, p_td_s, p_dl_s, p_dl_cw, p_dl_sw, p_dl_ssw, out, n);
}

// Round 8
// 54.302 us; speedup vs baseline: 1.5026x; 1.0859x over previous
//
#include <hip/hip_runtime.h>

// Elementwise fuzzify: y[r, i] = clip(diag[r] * aug_r(x[i]) + b[r], 0, 1).
// R8: A/B store path. Identical structure to R7 (ITERS=32, 128KB block chunk
// in VGPRs, 1 block/CU, row-grouped 128KB contiguous runs) but CACHED stores
// instead of nontemporal. Rationale: the harness fill kernel sustains 6.9 TB/s
// write with cached stores (L2 write-combine -> large channel-coherent
// evictions); our nt-store write phase only reaches ~5.6 TB/s. x is consumed
// into registers in the first ~5us, so L2 store pollution is harmless.

typedef float f32x4 __attribute__((ext_vector_type(4)));

constexpr int ITERS = 32;                   // float4s per thread (128 VGPRs)
constexpr int CHUNK_F4 = 256 * ITERS;       // 8192 float4s = 128 KB per block

__global__ __launch_bounds__(256, 1) void fuzzify_kernel(
    const float* __restrict__ x,
    const float* __restrict__ p_td_c,
    const float* __restrict__ p_td_s,
    const float* __restrict__ p_dl_s,
    const float* __restrict__ p_dl_cw,
    const float* __restrict__ p_dl_sw,
    const float* __restrict__ p_dl_ssw,
    float* __restrict__ out, int n)
{
    const float ms = 0.01f;
    const float td_c = p_td_c[0];
    const float td_s = fabsf(p_td_s[0] - ms) + ms;
    const float dl_s = fabsf(p_dl_s[0] - ms) + ms;

    const float slope_width = 1.0f / dl_s;
    const float cw  = fabsf(p_dl_cw[0]);
    const float sw  = fabsf(p_dl_sw[0]);
    const float ssw = fabsf(p_dl_ssw[0]);
    const float c_half  = 0.5f * cw;
    const float s_half  = 0.5f * sw;
    const float ss_half = 0.5f * ssw;

    const float d1 = dl_s * s_half + 1.0f;
    const float c1 = c_half + slope_width + s_half;
    const float d2 = dl_s * ss_half + 1.0f;
    const float c2 = c_half + 2.0f * slope_width + sw + ss_half;
    const float c3 = c_half + sw + 3.0f * slope_width + ssw;
    const float d3 = -dl_s * c3 + 1.0f;
    const float a  = td_c * td_s;

    // Row 2's aug = -x folded into slope: dl_s * (-x) == (-dl_s) * x.
    const float slope[9] = { -td_s, td_s, -dl_s, -dl_s, -dl_s, -dl_s, -dl_s, -dl_s, dl_s };
    const float bias[9]  = { 1.0f + a, -a, d3, d2, d1, dl_s * c_half + 1.0f, d1, d2, d3 };
    const float offs[9]  = { 0.0f, 0.0f, 0.0f, c2, c1, 0.0f, -c1, -c2, 0.0f };

    const int lane = threadIdx.x & 63;
    const int wav  = threadIdx.x >> 6;
    // wave w owns a contiguous 32KB span; block covers contiguous 128KB.
    const int i0 = blockIdx.x * CHUNK_F4 + wav * (64 * ITERS) + lane;

    const f32x4* __restrict__ x4 = (const f32x4*)x;

    // Load this thread's 32 float4s up front (independent -> deep MLP).
    f32x4 xv[ITERS];
    #pragma unroll
    for (int k = 0; k < ITERS; ++k)
        xv[k] = __builtin_nontemporal_load(&x4[i0 + k * 64]);

    // For each output row: 32 consecutive 1KB wave-runs back-to-back
    // (32KB contiguous per wave, 128KB per block, per stream). CACHED stores.
    #pragma unroll
    for (int r = 0; r < 9; ++r) {
        const float s  = slope[r];
        const float b  = bias[r];
        const float of = offs[r];
        const bool  is_abs = (r >= 3) && (r <= 7);
        float* __restrict__ orow = out + (size_t)r * (size_t)n;

        #pragma unroll
        for (int k = 0; k < ITERS; ++k) {
            f32x4 v = xv[k];
            f32x4 o;
            #pragma unroll
            for (int j = 0; j < 4; ++j) {
                float t = is_abs ? fabsf(v[j] + of) : v[j];
                float y = fmaf(s, t, b);
                o[j] = fminf(fmaxf(y, 0.0f), 1.0f);   // v_med3_f32
            }
            *(f32x4*)(orow + ((size_t)(i0 + k * 64) << 2)) = o;
        }
    }
}

extern "C" void kernel_launch(void* const* d_in, const int* in_sizes, int n_in,
                              void* d_out, int out_size, void* d_ws, size_t ws_size,
                              hipStream_t stream) {
    const float* x        = (const float*)d_in[0];
    const float* p_td_c   = (const float*)d_in[1];
    const float* p_td_s   = (const float*)d_in[2];
    const float* p_dl_s   = (const float*)d_in[3];
    const float* p_dl_cw  = (const float*)d_in[4];
    const float* p_dl_sw  = (const float*)d_in[5];
    const float* p_dl_ssw = (const float*)d_in[6];
    float* out = (float*)d_out;

    const int n = in_sizes[0];                 // 2^23
    const int n4 = n >> 2;                     // 2^21 float4s
    const int grid = n4 / CHUNK_F4;            // 256 blocks (exact) = 1/CU

    fuzzify_kernel<<<grid, 256, 0, stream>>>(
        x, p_td_c, p_td_s, p_dl_s, p_dl_cw, p_dl_sw, p_dl_ssw, out, n);
}